// Round 1
// baseline (254.648 us; speedup 1.0000x reference)
//
#include <hip/hip_runtime.h>

#define BB 32
#define NN 2048
#define DD 65
#define HH 64
#define DD2 (DD * DD)

__device__ __forceinline__ int waveid() {
  return __builtin_amdgcn_readfirstlane((int)(threadIdx.x >> 6));
}

// Kernel 1: partial Gram matrices P[b][c] = sum over row-chunk c of x_b^T x_b.
// Extra block (last) computes M = Wq^T Wk.
// Mapping: lane = output column j (0..63), wave = i-slice of 17 rows.
// Column 64 recovered from symmetry (G row 64), corner via scalar accumulate.
__global__ __launch_bounds__(256) void k1_partial_gram(
    const float* __restrict__ x, const float* __restrict__ Wq,
    const float* __restrict__ Wk, float* __restrict__ P,
    float* __restrict__ M, int C, int Rc) {
  const int lane = (int)(threadIdx.x & 63);
  const int w = waveid();
  const int i0 = w * 17;
  const int cnt = min(17, DD - i0);  // 17,17,17,14
  float acc[17];
#pragma unroll
  for (int q = 0; q < 17; q++) acc[q] = 0.f;

  const int blk = (int)blockIdx.x;
  if (blk < BB * C) {
    const int b = blk / C;
    const int c = blk - b * C;
    const float* xb = x + ((size_t)b * NN + (size_t)c * Rc) * DD;
    float accD = 0.f;
    for (int n = 0; n < Rc; n++) {
      const float* xr = xb + (size_t)n * DD;
      const float v = xr[lane];  // coalesced vector load
#pragma unroll
      for (int q = 0; q < 17; q++) {
        // xr[...] is wave-uniform -> scalar (SMEM) load path
        acc[q] = fmaf(xr[min(i0 + q, DD - 1)], v, acc[q]);
      }
      if (w == 3) {
        const float s = xr[DD - 1];
        accD = fmaf(s, s, accD);
      }
    }
    float* Pp = P + (size_t)blk * DD2;
    for (int q = 0; q < cnt; q++) {
      const int i = i0 + q;
      Pp[i * DD + lane] = acc[q];
      if (i == DD - 1) Pp[lane * DD + (DD - 1)] = acc[q];  // symmetry
    }
    if (w == 3 && lane == 0) Pp[(DD - 1) * DD + (DD - 1)] = accD;
  } else {
    // M[i][j] = sum_h Wq[h][i] * Wk[h][j]
    float a64 = 0.f, aDD = 0.f;
    for (int h = 0; h < HH; h++) {
      const float vk = Wk[h * DD + lane];
#pragma unroll
      for (int q = 0; q < 17; q++) {
        acc[q] = fmaf(Wq[h * DD + min(i0 + q, DD - 1)], vk, acc[q]);
      }
      if (w == 0) {
        const float vq = Wq[h * DD + lane];
        const float sk = Wk[h * DD + (DD - 1)];
        a64 = fmaf(vq, sk, a64);
        aDD = fmaf(Wq[h * DD + (DD - 1)], sk, aDD);
      }
    }
    for (int q = 0; q < cnt; q++) M[(i0 + q) * DD + lane] = acc[q];
    if (w == 0) {
      M[lane * DD + (DD - 1)] = a64;  // M[i][64], i<64
      if (lane == 0) M[(DD - 1) * DD + (DD - 1)] = aDD;
    }
  }
}

// Kernel 2: one block per batch.
//   a) G = sum_c P[b][c]            (into LDS)
//   b) R = M * G                    (A via uniform s_load from global M, B from LDS)
//   c) Tt[j][i] = T[i][j], T = R*Wv^T  (A via uniform s_load from global Wv, B from LDS)
// T stored TRANSPOSED so kernel 3 gets contiguous per-lane columns.
__global__ __launch_bounds__(256) void k2_small_chain(
    const float* __restrict__ Wv, const float* __restrict__ P,
    const float* __restrict__ M, float* __restrict__ Tt, int C) {
  __shared__ float Gl[DD2];
  __shared__ float Rl[DD2];
  __shared__ float Ml[DD2];
  __shared__ float Wvl[DD2];
  const int b = (int)blockIdx.x;
  const int t = (int)threadIdx.x;
  for (int idx = t; idx < DD2; idx += 256) {
    float s = 0.f;
    const float* Pb = P + (size_t)b * C * DD2 + idx;
    for (int c = 0; c < C; c++) s += Pb[(size_t)c * DD2];
    Gl[idx] = s;
    Ml[idx] = M[idx];
    Wvl[idx] = Wv[idx];
  }
  __syncthreads();
  const int lane = t & 63;
  const int w = waveid();
  const int i0 = w * 17;
  const int cnt = min(17, DD - i0);

  // Stage 1: R[i][j] = sum_k M[i][k] * G[k][j]   (lane = j)
  {
    float acc[17];
#pragma unroll
    for (int q = 0; q < 17; q++) acc[q] = 0.f;
    for (int k = 0; k < DD; k++) {
      const float g = Gl[k * DD + lane];  // bank (k+lane)%32: 2-way, free
#pragma unroll
      for (int q = 0; q < 17; q++)
        acc[q] = fmaf(M[min(i0 + q, DD - 1) * DD + k], g, acc[q]);  // s_load
    }
    for (int q = 0; q < cnt; q++) Rl[(i0 + q) * DD + lane] = acc[q];
    if (w == 0) {  // R[i][64], i = lane < 64
      float a = 0.f;
      for (int k = 0; k < DD; k++)
        a = fmaf(Ml[lane * DD + k], Gl[k * DD + (DD - 1)], a);
      Rl[lane * DD + (DD - 1)] = a;
    } else if (w == 1) {  // R[64][64]
      float a = 0.f;
      for (int k = 0; k < DD; k++)
        a = fmaf(Ml[(DD - 1) * DD + k], Gl[k * DD + (DD - 1)], a);
      if (lane == 0) Rl[(DD - 1) * DD + (DD - 1)] = a;
    }
  }
  __syncthreads();

  // Stage 2: Tt[j][i] = sum_k R[i][k] * Wv[j][k]   (lane = i, wave = j-slice)
  {
    float acc[17];
#pragma unroll
    for (int q = 0; q < 17; q++) acc[q] = 0.f;
    for (int k = 0; k < DD; k++) {
      const float r = Rl[lane * DD + k];  // bank (lane+k)%32: 2-way, free
#pragma unroll
      for (int q = 0; q < 17; q++)
        acc[q] = fmaf(Wv[min(i0 + q, DD - 1) * DD + k], r, acc[q]);  // s_load
    }
    float* Tb = Tt + (size_t)b * DD2;
    for (int q = 0; q < cnt; q++) Tb[(i0 + q) * DD + lane] = acc[q];
    if (w == 0) {  // Tt[j][64] = T[64][j] = sum_k R[64][k] Wv[j][k], j = lane < 64
      float a = 0.f;
      for (int k = 0; k < DD; k++)
        a = fmaf(Rl[(DD - 1) * DD + k], Wvl[lane * DD + k], a);
      Tb[lane * DD + (DD - 1)] = a;
    } else if (w == 2) {  // Tt[64][64] = T[64][64]
      float a = 0.f;
      for (int k = 0; k < DD; k++)
        a = fmaf(Rl[(DD - 1) * DD + k], Wv[(DD - 1) * DD + k], a);
      if (lane == 0) Tb[(DD - 1) * DD + (DD - 1)] = a;
    }
  }
}

// Kernel 3: out[b] = x[b] @ T[b].  128 rows per block.
// Waves 0-3: lane = output column j (0..63), T[:,j] held in 65 VGPRs,
//            x-row scalars via uniform s_load. 32 rows per wave.
// Wave 4: output column 64 for all 128 rows (lane = row), x staged in LDS.
__global__ __launch_bounds__(320) void k3_out(const float* __restrict__ x,
                                              const float* __restrict__ Tt,
                                              float* __restrict__ out) {
  __shared__ float Tl[DD2];
  __shared__ float Xl[128 * DD];
  const int blk = (int)blockIdx.x;
  const int b = blk >> 4;             // 16 blocks per batch
  const int rbase = (blk & 15) * 128;
  const int t = (int)threadIdx.x;
  const int lane = t & 63;
  const int w = waveid();
  for (int idx = t; idx < DD2; idx += 320) Tl[idx] = Tt[(size_t)b * DD2 + idx];
  __syncthreads();

  if (w < 4) {
    float Tc[DD];
#pragma unroll
    for (int k = 0; k < DD; k++) Tc[k] = Tl[lane * DD + k];  // T[:,lane]
    const size_t row0 = (size_t)b * NN + rbase + w * 32;
    const float* xb = x + row0 * DD;
    float* ob = out + row0 * DD;
    for (int r = 0; r < 32; r++) {
      const float* xr = xb + r * DD;
      float a0 = 0.f, a1 = 0.f, a2 = 0.f, a3 = 0.f;
#pragma unroll
      for (int k = 0; k < 64; k += 4) {
        a0 = fmaf(xr[k], Tc[k], a0);
        a1 = fmaf(xr[k + 1], Tc[k + 1], a1);
        a2 = fmaf(xr[k + 2], Tc[k + 2], a2);
        a3 = fmaf(xr[k + 3], Tc[k + 3], a3);
      }
      a0 = fmaf(xr[64], Tc[64], a0);
      ob[r * DD + lane] = (a0 + a1) + (a2 + a3);
    }
  } else {
    // stage this block's x rows (coalesced), then col-64 matvec, lane = row
    const float* xb = x + ((size_t)b * NN + rbase) * DD;
    for (int idx = lane; idx < 128 * DD; idx += 64) Xl[idx] = xb[idx];
    for (int g = 0; g < 2; g++) {
      const int rr = g * 64 + lane;
      float a0 = 0.f, a1 = 0.f;
#pragma unroll
      for (int k = 0; k < 64; k += 2) {
        a0 = fmaf(Xl[rr * DD + k], Tl[(DD - 1) * DD + k], a0);
        a1 = fmaf(Xl[rr * DD + k + 1], Tl[(DD - 1) * DD + k + 1], a1);
      }
      a0 = fmaf(Xl[rr * DD + 64], Tl[(DD - 1) * DD + 64], a0);
      out[((size_t)b * NN + rbase + rr) * DD + (DD - 1)] = a0 + a1;
    }
  }
}

extern "C" void kernel_launch(void* const* d_in, const int* in_sizes, int n_in,
                              void* d_out, int out_size, void* d_ws,
                              size_t ws_size, hipStream_t stream) {
  const float* x = (const float*)d_in[0];
  const float* Wq = (const float*)d_in[1];
  const float* Wk = (const float*)d_in[2];
  const float* Wv = (const float*)d_in[3];
  float* out = (float*)d_out;

  // Workspace: P[B*C][65*65] partial Grams, M[65*65], Tt[B][65*65].
  int C = 16;
  while (C > 1 &&
         (size_t)(BB * C + 1 + BB) * DD2 * sizeof(float) > ws_size)
    C >>= 1;
  const int Rc = NN / C;
  float* P = (float*)d_ws;
  float* M = P + (size_t)BB * C * DD2;
  float* Tt = M + DD2;

  k1_partial_gram<<<BB * C + 1, 256, 0, stream>>>(x, Wq, Wk, P, M, C, Rc);
  k2_small_chain<<<BB, 256, 0, stream>>>(Wv, P, M, Tt, C);
  k3_out<<<BB * 16, 320, 0, stream>>>(x, Tt, out);
  (void)in_sizes; (void)n_in; (void)out_size; (void)ws_size;
}

// Round 2
// 203.875 us; speedup vs baseline: 1.2490x; 1.2490x over previous
//
#include <hip/hip_runtime.h>

#define BB 32
#define NN 2048
#define DD 65
#define HH 64
#define ST 68                // padded leading dim (16B-aligned float4 frags)
#define TILE (DD * ST)       // 4420 floats per padded 65x65 matrix

// ---------------------------------------------------------------------------
// k1: partial Gram P[b][c] = (x chunk)^T (x chunk), 65x65, stride-68 tiles.
// 16x16 threads, 4x4 regs each over the 64x64 core; ty==0 threads patch
// row/col 64 via symmetry. All operands via LDS float4 frags (no s_loads).
// ---------------------------------------------------------------------------
__global__ __launch_bounds__(256) void k1_gram(const float* __restrict__ x,
                                               float* __restrict__ P,
                                               int C, int Rc) {
  __shared__ float Xl[64 * ST];
  const int t = (int)threadIdx.x;
  const int tx = t & 15, ty = t >> 4;
  const int blk = (int)blockIdx.x;
  const int b = blk / C, c = blk - b * C;
  const float* xb = x + ((size_t)b * NN + (size_t)c * Rc) * DD;

  float g[4][4] = {};
  float g64[4] = {};
  float gcc = 0.f;

  const int rounds = Rc >> 6;
  for (int rd = 0; rd < rounds; rd++) {
    const float* src = xb + (size_t)rd * (64 * DD);
    for (int idx = t; idx < 64 * DD; idx += 256) {
      int r = idx / DD;
      Xl[r * ST + (idx - r * DD)] = src[idx];
    }
    __syncthreads();
    for (int n = 0; n < 64; n++) {
      float rowf[4], colf[4];
      *(float4*)rowf = *(const float4*)&Xl[n * ST + 4 * ty];  // 4 addrs: free
      *(float4*)colf = *(const float4*)&Xl[n * ST + 4 * tx];  // 2-way: free
#pragma unroll
      for (int r = 0; r < 4; r++)
#pragma unroll
        for (int cc = 0; cc < 4; cc++)
          g[r][cc] = fmaf(rowf[r], colf[cc], g[r][cc]);
      if (ty == 0) {
        float x64 = Xl[n * ST + 64];
#pragma unroll
        for (int cc = 0; cc < 4; cc++) g64[cc] = fmaf(x64, colf[cc], g64[cc]);
        if (tx == 0) gcc = fmaf(x64, x64, gcc);
      }
    }
    __syncthreads();
  }
  float* Pp = P + (size_t)blk * TILE;
#pragma unroll
  for (int r = 0; r < 4; r++)
    *(float4*)&Pp[(4 * ty + r) * ST + 4 * tx] = *(float4*)g[r];
  if (ty == 0) {
    *(float4*)&Pp[64 * ST + 4 * tx] = *(float4*)g64;  // G[64][j]
#pragma unroll
    for (int cc = 0; cc < 4; cc++)
      Pp[(4 * tx + cc) * ST + 64] = g64[cc];          // G[i][64] by symmetry
    if (tx == 0) Pp[64 * ST + 64] = gcc;
  }
}

// ---------------------------------------------------------------------------
// k2: per batch: G = sum_c P; M = Wq^T Wk; R = M G; T = R Wv^T (row-major).
// Two 65x68 LDS buffers reused: A: Wq -> M -> R;  B: Wk -> G -> Wv^T.
// Same 16x16 / 4x4 tiling; edge patches for index 64. No global s_loads in
// any inner loop.
// ---------------------------------------------------------------------------
__global__ __launch_bounds__(256) void k2_chain(
    const float* __restrict__ Wq, const float* __restrict__ Wk,
    const float* __restrict__ Wv, const float* __restrict__ P,
    float* __restrict__ Tm, int C) {
  __shared__ float A[TILE];
  __shared__ float Bf[TILE];
  const int t = (int)threadIdx.x;
  const int tx = t & 15, ty = t >> 4;
  const int b = (int)blockIdx.x;

  // phase 0: stage Wq -> A, Wk -> B (64 rows x 65 cols, stride 68)
  for (int idx = t; idx < HH * DD; idx += 256) {
    int r = idx / DD, cc = idx - r * DD;
    A[r * ST + cc] = Wq[idx];
    Bf[r * ST + cc] = Wk[idx];
  }
  __syncthreads();

  // phase 1: M[i][j] = sum_h Wq[h][i] Wk[h][j] (in regs)
  float m[4][4] = {}, mrow[4] = {}, mcol[4] = {}, mcc = 0.f;
  for (int h = 0; h < HH; h++) {
    float qa[4], kb[4];
    *(float4*)qa = *(const float4*)&A[h * ST + 4 * ty];
    *(float4*)kb = *(const float4*)&Bf[h * ST + 4 * tx];
#pragma unroll
    for (int r = 0; r < 4; r++)
#pragma unroll
      for (int cc = 0; cc < 4; cc++) m[r][cc] = fmaf(qa[r], kb[cc], m[r][cc]);
    if (ty == 0) {
      float q64 = A[h * ST + 64];
#pragma unroll
      for (int cc = 0; cc < 4; cc++) mrow[cc] = fmaf(q64, kb[cc], mrow[cc]);
    }
    if (tx == 0) {
      float k64 = Bf[h * ST + 64];
#pragma unroll
      for (int r = 0; r < 4; r++) mcol[r] = fmaf(qa[r], k64, mcol[r]);
      if (ty == 0) mcc = fmaf(A[h * ST + 64], k64, mcc);
    }
  }
  __syncthreads();

  // phase 2: write M -> A; reduce P -> B (G)
#pragma unroll
  for (int r = 0; r < 4; r++)
    *(float4*)&A[(4 * ty + r) * ST + 4 * tx] = *(float4*)m[r];
  if (ty == 0) *(float4*)&A[64 * ST + 4 * tx] = *(float4*)mrow;
  if (tx == 0) {
#pragma unroll
    for (int r = 0; r < 4; r++) A[(4 * ty + r) * ST + 64] = mcol[r];
  }
  if (t == 0) A[64 * ST + 64] = mcc;
  {
    const float* Pb = P + (size_t)b * C * TILE;
    for (int idx = t; idx < TILE; idx += 256) {
      float s = 0.f;
      for (int cc = 0; cc < C; cc++) s += Pb[(size_t)cc * TILE + idx];
      Bf[idx] = s;
    }
  }
  __syncthreads();

  // phase 3: R[i][j] = sum_k M[i][k] G[k][j] (in regs)
  float rr[4][4] = {}, r64j[4] = {}, ri64[4] = {}, rcc = 0.f;
  for (int k = 0; k < DD; k++) {
    float gb[4], ma[4];
    *(float4*)gb = *(const float4*)&Bf[k * ST + 4 * tx];
#pragma unroll
    for (int r = 0; r < 4; r++) ma[r] = A[(4 * ty + r) * ST + k];
#pragma unroll
    for (int r = 0; r < 4; r++)
#pragma unroll
      for (int cc = 0; cc < 4; cc++)
        rr[r][cc] = fmaf(ma[r], gb[cc], rr[r][cc]);
    if (ty == 0) {
      float m64 = A[64 * ST + k];
#pragma unroll
      for (int cc = 0; cc < 4; cc++) r64j[cc] = fmaf(m64, gb[cc], r64j[cc]);
    }
    if (tx == 0) {
      float g64 = Bf[k * ST + 64];
#pragma unroll
      for (int r = 0; r < 4; r++) ri64[r] = fmaf(ma[r], g64, ri64[r]);
      if (ty == 0) rcc = fmaf(A[64 * ST + k], g64, rcc);
    }
  }
  __syncthreads();

  // phase 4: write R -> A; stage Wv^T -> B  (Bf[k][j] = Wv[j][k])
#pragma unroll
  for (int r = 0; r < 4; r++)
    *(float4*)&A[(4 * ty + r) * ST + 4 * tx] = *(float4*)rr[r];
  if (ty == 0) *(float4*)&A[64 * ST + 4 * tx] = *(float4*)r64j;
  if (tx == 0) {
#pragma unroll
    for (int r = 0; r < 4; r++) A[(4 * ty + r) * ST + 64] = ri64[r];
  }
  if (t == 0) A[64 * ST + 64] = rcc;
  for (int idx = t; idx < DD * DD; idx += 256) {
    int j = idx / DD, k = idx - j * DD;
    Bf[k * ST + j] = Wv[idx];
  }
  __syncthreads();

  // phase 5: T[i][j] = sum_k R[i][k] Wv[j][k]; i = 4ty+ir, j = 4tx+jc
  float tt[4][4] = {}, row64[4] = {}, col64[4] = {}, tcc = 0.f;
  for (int k = 0; k < DD; k++) {
    float wv[4], ra[4];
    *(float4*)wv = *(const float4*)&Bf[k * ST + 4 * tx];  // Wv[4tx+jc][k]
#pragma unroll
    for (int ir = 0; ir < 4; ir++) ra[ir] = A[(4 * ty + ir) * ST + k];
#pragma unroll
    for (int ir = 0; ir < 4; ir++)
#pragma unroll
      for (int jc = 0; jc < 4; jc++)
        tt[ir][jc] = fmaf(ra[ir], wv[jc], tt[ir][jc]);
    if (ty == 0) {
      float r64 = A[64 * ST + k];  // R[64][k]
#pragma unroll
      for (int jc = 0; jc < 4; jc++) row64[jc] = fmaf(r64, wv[jc], row64[jc]);
    }
    if (tx == 0) {
      float w64 = Bf[k * ST + 64];  // Wv[64][k]
#pragma unroll
      for (int ir = 0; ir < 4; ir++) col64[ir] = fmaf(ra[ir], w64, col64[ir]);
      if (ty == 0) tcc = fmaf(A[64 * ST + k], w64, tcc);
    }
  }
  float* Tb = Tm + (size_t)b * TILE;
#pragma unroll
  for (int ir = 0; ir < 4; ir++)
    *(float4*)&Tb[(4 * ty + ir) * ST + 4 * tx] = *(float4*)tt[ir];
  if (ty == 0) *(float4*)&Tb[64 * ST + 4 * tx] = *(float4*)row64;  // T[64][j]
  if (tx == 0) {
#pragma unroll
    for (int ir = 0; ir < 4; ir++)
      Tb[(4 * ty + ir) * ST + 64] = col64[ir];                     // T[i][64]
  }
  if (t == 0) Tb[64 * ST + 64] = tcc;
}

// ---------------------------------------------------------------------------
// k3: out[b] = x[b] @ T[b]. 64 rows per block; x-tile + T staged in LDS,
// same 4x4 register tiling; tx==0 patches output column 64.
// ---------------------------------------------------------------------------
__global__ __launch_bounds__(256) void k3_out(const float* __restrict__ x,
                                              const float* __restrict__ Tt,
                                              float* __restrict__ out) {
  __shared__ float Tl[TILE];
  __shared__ float Xl[64 * ST];
  const int t = (int)threadIdx.x;
  const int tx = t & 15, ty = t >> 4;
  const int blk = (int)blockIdx.x;
  const int b = blk >> 5;           // 32 blocks per batch
  const int rb = (blk & 31) * 64;
  const float* Tg = Tt + (size_t)b * TILE;
  for (int idx = t; idx < TILE; idx += 256) Tl[idx] = Tg[idx];
  const float* src = x + ((size_t)b * NN + rb) * DD;
  for (int idx = t; idx < 64 * DD; idx += 256) {
    int r = idx / DD;
    Xl[r * ST + (idx - r * DD)] = src[idx];
  }
  __syncthreads();

  float o[4][4] = {}, o64[4] = {};
  for (int k = 0; k < DD; k++) {
    float xa[4], tb[4];
#pragma unroll
    for (int r = 0; r < 4; r++) xa[r] = Xl[(4 * ty + r) * ST + k];
    *(float4*)tb = *(const float4*)&Tl[k * ST + 4 * tx];
#pragma unroll
    for (int r = 0; r < 4; r++)
#pragma unroll
      for (int cc = 0; cc < 4; cc++) o[r][cc] = fmaf(xa[r], tb[cc], o[r][cc]);
    if (tx == 0) {
      float t64 = Tl[k * ST + 64];
#pragma unroll
      for (int r = 0; r < 4; r++) o64[r] = fmaf(xa[r], t64, o64[r]);
    }
  }
  float* ob = out + ((size_t)b * NN + rb) * DD;
#pragma unroll
  for (int r = 0; r < 4; r++)
#pragma unroll
    for (int cc = 0; cc < 4; cc++)
      ob[(4 * ty + r) * DD + 4 * tx + cc] = o[r][cc];
  if (tx == 0) {
#pragma unroll
    for (int r = 0; r < 4; r++) ob[(4 * ty + r) * DD + 64] = o64[r];
  }
}

extern "C" void kernel_launch(void* const* d_in, const int* in_sizes, int n_in,
                              void* d_out, int out_size, void* d_ws,
                              size_t ws_size, hipStream_t stream) {
  const float* x = (const float*)d_in[0];
  const float* Wq = (const float*)d_in[1];
  const float* Wk = (const float*)d_in[2];
  const float* Wv = (const float*)d_in[3];
  float* out = (float*)d_out;

  // Workspace: P[B*C] padded 65x68 tiles + T[B] padded tiles.
  int C = 16;
  while (C > 1 && (size_t)(BB * C + BB) * TILE * sizeof(float) > ws_size)
    C >>= 1;
  const int Rc = NN / C;
  float* P = (float*)d_ws;
  float* Tm = P + (size_t)BB * C * TILE;

  k1_gram<<<BB * C, 256, 0, stream>>>(x, P, C, Rc);
  k2_chain<<<BB, 256, 0, stream>>>(Wq, Wk, Wv, P, Tm, C);
  k3_out<<<BB * 32, 256, 0, stream>>>(x, Tm, out);
  (void)in_sizes; (void)n_in; (void)out_size; (void)ws_size;
}

// Round 3
// 150.081 us; speedup vs baseline: 1.6967x; 1.3584x over previous
//
#include <hip/hip_runtime.h>

#define BB 32
#define NN 2048
#define DD 65
#define HH 64
#define ST 68                // padded leading dim (16B-aligned float4 frags)
#define TILE (DD * ST)       // 4420 floats per padded 65x65 matrix

// ---------------------------------------------------------------------------
// k1: partial Gram P[b][c] = (x chunk)^T (x chunk), 65x65, stride-68 tiles.
// 16x16 threads, 4x4 regs each over the 64x64 core; ty==0 threads patch
// row/col 64 via symmetry. Staging: batched register pre-load (17 loads in
// flight) + cross-round software pipeline.
// ---------------------------------------------------------------------------
__global__ __launch_bounds__(256) void k1_gram(const float* __restrict__ x,
                                               float* __restrict__ P,
                                               int C, int Rc) {
  __shared__ float Xl[64 * ST];
  const int t = (int)threadIdx.x;
  const int tx = t & 15, ty = t >> 4;
  const int blk = (int)blockIdx.x;
  const int b = blk / C, c = blk - b * C;
  const float* xb = x + ((size_t)b * NN + (size_t)c * Rc) * DD;

  float g[4][4] = {};
  float g64[4] = {};
  float gcc = 0.f;

  const int rounds = Rc >> 6;
  float tmp[17];
  {  // prefetch round 0 (17 independent loads in flight)
    const float* src = xb;
#pragma unroll
    for (int q = 0; q < 17; q++) {
      const int idx = t + 256 * q;
      if (idx < 64 * DD) tmp[q] = src[idx];
    }
  }
  for (int rd = 0; rd < rounds; rd++) {
#pragma unroll
    for (int q = 0; q < 17; q++) {
      const int idx = t + 256 * q;
      if (idx < 64 * DD) {
        const int r = idx / DD;
        Xl[r * ST + (idx - r * DD)] = tmp[q];
      }
    }
    __syncthreads();
    if (rd + 1 < rounds) {  // prefetch next round during compute
      const float* src = xb + (size_t)(rd + 1) * (64 * DD);
#pragma unroll
      for (int q = 0; q < 17; q++) {
        const int idx = t + 256 * q;
        if (idx < 64 * DD) tmp[q] = src[idx];
      }
    }
    for (int n = 0; n < 64; n++) {
      float rowf[4], colf[4];
      *(float4*)rowf = *(const float4*)&Xl[n * ST + 4 * ty];
      *(float4*)colf = *(const float4*)&Xl[n * ST + 4 * tx];
#pragma unroll
      for (int r = 0; r < 4; r++)
#pragma unroll
        for (int cc = 0; cc < 4; cc++)
          g[r][cc] = fmaf(rowf[r], colf[cc], g[r][cc]);
      if (ty == 0) {
        float x64 = Xl[n * ST + 64];
#pragma unroll
        for (int cc = 0; cc < 4; cc++) g64[cc] = fmaf(x64, colf[cc], g64[cc]);
        if (tx == 0) gcc = fmaf(x64, x64, gcc);
      }
    }
    __syncthreads();
  }
  float* Pp = P + (size_t)blk * TILE;
#pragma unroll
  for (int r = 0; r < 4; r++)
    *(float4*)&Pp[(4 * ty + r) * ST + 4 * tx] = *(float4*)g[r];
  if (ty == 0) {
    *(float4*)&Pp[64 * ST + 4 * tx] = *(float4*)g64;  // G[64][j]
#pragma unroll
    for (int cc = 0; cc < 4; cc++)
      Pp[(4 * tx + cc) * ST + 64] = g64[cc];          // G[i][64] by symmetry
    if (tx == 0) Pp[64 * ST + 64] = gcc;
  }
}

// ---------------------------------------------------------------------------
// k2: per batch: G = sum_c P; M = Wq^T Wk; R = M G; T = R Wv^T.
// Templated on C so the partial-Gram reduction fully unrolls (C loads in
// flight per slot). All staging loops batched through registers.
// ---------------------------------------------------------------------------
template <int C>
__global__ __launch_bounds__(256) void k2_chain(
    const float* __restrict__ Wq, const float* __restrict__ Wk,
    const float* __restrict__ Wv, const float* __restrict__ P,
    float* __restrict__ Tm) {
  __shared__ float A[TILE];
  __shared__ float Bf[TILE];
  const int t = (int)threadIdx.x;
  const int tx = t & 15, ty = t >> 4;
  const int b = (int)blockIdx.x;

  // phase 0: stage Wq -> A, Wk -> B (batched: 34 loads in flight)
  {
    float tq[17], tk[17];
#pragma unroll
    for (int q = 0; q < 17; q++) {
      const int idx = t + 256 * q;
      if (idx < HH * DD) { tq[q] = Wq[idx]; tk[q] = Wk[idx]; }
    }
#pragma unroll
    for (int q = 0; q < 17; q++) {
      const int idx = t + 256 * q;
      if (idx < HH * DD) {
        const int r = idx / DD, cc = idx - r * DD;
        A[r * ST + cc] = tq[q];
        Bf[r * ST + cc] = tk[q];
      }
    }
  }
  __syncthreads();

  // phase 1: M[i][j] = sum_h Wq[h][i] Wk[h][j] (in regs)
  float m[4][4] = {}, mrow[4] = {}, mcol[4] = {}, mcc = 0.f;
  for (int h = 0; h < HH; h++) {
    float qa[4], kb[4];
    *(float4*)qa = *(const float4*)&A[h * ST + 4 * ty];
    *(float4*)kb = *(const float4*)&Bf[h * ST + 4 * tx];
#pragma unroll
    for (int r = 0; r < 4; r++)
#pragma unroll
      for (int cc = 0; cc < 4; cc++) m[r][cc] = fmaf(qa[r], kb[cc], m[r][cc]);
    if (ty == 0) {
      float q64 = A[h * ST + 64];
#pragma unroll
      for (int cc = 0; cc < 4; cc++) mrow[cc] = fmaf(q64, kb[cc], mrow[cc]);
    }
    if (tx == 0) {
      float k64 = Bf[h * ST + 64];
#pragma unroll
      for (int r = 0; r < 4; r++) mcol[r] = fmaf(qa[r], k64, mcol[r]);
      if (ty == 0) mcc = fmaf(A[h * ST + 64], k64, mcc);
    }
  }
  __syncthreads();

  // phase 2: write M -> A; reduce P -> B (G). Inner C-loop fully unrolled:
  // C independent loads in flight per slot.
#pragma unroll
  for (int r = 0; r < 4; r++)
    *(float4*)&A[(4 * ty + r) * ST + 4 * tx] = *(float4*)m[r];
  if (ty == 0) *(float4*)&A[64 * ST + 4 * tx] = *(float4*)mrow;
  if (tx == 0) {
#pragma unroll
    for (int r = 0; r < 4; r++) A[(4 * ty + r) * ST + 64] = mcol[r];
  }
  if (t == 0) A[64 * ST + 64] = mcc;
  {
    const float* Pb = P + (size_t)b * C * TILE;
    for (int idx = t; idx < TILE; idx += 256) {
      float s = 0.f;
#pragma unroll
      for (int cc = 0; cc < C; cc++) s += Pb[(size_t)cc * TILE + idx];
      Bf[idx] = s;
    }
  }
  __syncthreads();

  // phase 3: R[i][j] = sum_k M[i][k] G[k][j] (in regs)
  float rr[4][4] = {}, r64j[4] = {}, ri64[4] = {}, rcc = 0.f;
  for (int k = 0; k < DD; k++) {
    float gb[4], ma[4];
    *(float4*)gb = *(const float4*)&Bf[k * ST + 4 * tx];
#pragma unroll
    for (int r = 0; r < 4; r++) ma[r] = A[(4 * ty + r) * ST + k];
#pragma unroll
    for (int r = 0; r < 4; r++)
#pragma unroll
      for (int cc = 0; cc < 4; cc++)
        rr[r][cc] = fmaf(ma[r], gb[cc], rr[r][cc]);
    if (ty == 0) {
      float m64 = A[64 * ST + k];
#pragma unroll
      for (int cc = 0; cc < 4; cc++) r64j[cc] = fmaf(m64, gb[cc], r64j[cc]);
    }
    if (tx == 0) {
      float g64 = Bf[k * ST + 64];
#pragma unroll
      for (int r = 0; r < 4; r++) ri64[r] = fmaf(ma[r], g64, ri64[r]);
      if (ty == 0) rcc = fmaf(A[64 * ST + k], g64, rcc);
    }
  }
  __syncthreads();

  // phase 4: write R -> A; stage Wv^T -> B (batched)
#pragma unroll
  for (int r = 0; r < 4; r++)
    *(float4*)&A[(4 * ty + r) * ST + 4 * tx] = *(float4*)rr[r];
  if (ty == 0) *(float4*)&A[64 * ST + 4 * tx] = *(float4*)r64j;
  if (tx == 0) {
#pragma unroll
    for (int r = 0; r < 4; r++) A[(4 * ty + r) * ST + 64] = ri64[r];
  }
  if (t == 0) A[64 * ST + 64] = rcc;
  {
    float tv[17];
#pragma unroll
    for (int q = 0; q < 17; q++) {
      const int idx = t + 256 * q;
      if (idx < DD * DD) tv[q] = Wv[idx];
    }
#pragma unroll
    for (int q = 0; q < 17; q++) {
      const int idx = t + 256 * q;
      if (idx < DD * DD) {
        const int j = idx / DD, k = idx - j * DD;
        Bf[k * ST + j] = tv[q];
      }
    }
  }
  __syncthreads();

  // phase 5: T[i][j] = sum_k R[i][k] Wv[j][k]
  float tt[4][4] = {}, row64[4] = {}, col64[4] = {}, tcc = 0.f;
  for (int k = 0; k < DD; k++) {
    float wv[4], ra[4];
    *(float4*)wv = *(const float4*)&Bf[k * ST + 4 * tx];
#pragma unroll
    for (int ir = 0; ir < 4; ir++) ra[ir] = A[(4 * ty + ir) * ST + k];
#pragma unroll
    for (int ir = 0; ir < 4; ir++)
#pragma unroll
      for (int jc = 0; jc < 4; jc++)
        tt[ir][jc] = fmaf(ra[ir], wv[jc], tt[ir][jc]);
    if (ty == 0) {
      float r64 = A[64 * ST + k];
#pragma unroll
      for (int jc = 0; jc < 4; jc++) row64[jc] = fmaf(r64, wv[jc], row64[jc]);
    }
    if (tx == 0) {
      float w64 = Bf[k * ST + 64];
#pragma unroll
      for (int ir = 0; ir < 4; ir++) col64[ir] = fmaf(ra[ir], w64, col64[ir]);
      if (ty == 0) tcc = fmaf(A[64 * ST + k], w64, tcc);
    }
  }
  float* Tb = Tm + (size_t)b * TILE;
#pragma unroll
  for (int ir = 0; ir < 4; ir++)
    *(float4*)&Tb[(4 * ty + ir) * ST + 4 * tx] = *(float4*)tt[ir];
  if (ty == 0) *(float4*)&Tb[64 * ST + 4 * tx] = *(float4*)row64;  // T[64][j]
  if (tx == 0) {
#pragma unroll
    for (int ir = 0; ir < 4; ir++)
      Tb[(4 * ty + ir) * ST + 64] = col64[ir];                     // T[i][64]
  }
  if (t == 0) Tb[64 * ST + 64] = tcc;
}

// ---------------------------------------------------------------------------
// k3: out[b] = x[b] @ T[b]. 64 rows per block; batched register staging of
// T and x (35 loads in flight), then 4x4 register tiling from LDS.
// ---------------------------------------------------------------------------
__global__ __launch_bounds__(256) void k3_out(const float* __restrict__ x,
                                              const float* __restrict__ Tt,
                                              float* __restrict__ out) {
  __shared__ float Tl[TILE];
  __shared__ float Xl[64 * ST];
  const int t = (int)threadIdx.x;
  const int tx = t & 15, ty = t >> 4;
  const int blk = (int)blockIdx.x;
  const int b = blk >> 5;           // 32 blocks per batch
  const int rb = (blk & 31) * 64;
  const float* Tg = Tt + (size_t)b * TILE;
  const float* src = x + ((size_t)b * NN + rb) * DD;
  {
    float tT[18], tX[17];
#pragma unroll
    for (int q = 0; q < 18; q++) {
      const int idx = t + 256 * q;
      if (idx < TILE) tT[q] = Tg[idx];
    }
#pragma unroll
    for (int q = 0; q < 17; q++) {
      const int idx = t + 256 * q;
      if (idx < 64 * DD) tX[q] = src[idx];
    }
#pragma unroll
    for (int q = 0; q < 18; q++) {
      const int idx = t + 256 * q;
      if (idx < TILE) Tl[idx] = tT[q];
    }
#pragma unroll
    for (int q = 0; q < 17; q++) {
      const int idx = t + 256 * q;
      if (idx < 64 * DD) {
        const int r = idx / DD;
        Xl[r * ST + (idx - r * DD)] = tX[q];
      }
    }
  }
  __syncthreads();

  float o[4][4] = {}, o64[4] = {};
  for (int k = 0; k < DD; k++) {
    float xa[4], tb[4];
#pragma unroll
    for (int r = 0; r < 4; r++) xa[r] = Xl[(4 * ty + r) * ST + k];
    *(float4*)tb = *(const float4*)&Tl[k * ST + 4 * tx];
#pragma unroll
    for (int r = 0; r < 4; r++)
#pragma unroll
      for (int cc = 0; cc < 4; cc++) o[r][cc] = fmaf(xa[r], tb[cc], o[r][cc]);
    if (tx == 0) {
      float t64 = Tl[k * ST + 64];
#pragma unroll
      for (int r = 0; r < 4; r++) o64[r] = fmaf(xa[r], t64, o64[r]);
    }
  }
  float* ob = out + ((size_t)b * NN + rb) * DD;
#pragma unroll
  for (int r = 0; r < 4; r++)
#pragma unroll
    for (int cc = 0; cc < 4; cc++)
      ob[(4 * ty + r) * DD + 4 * tx + cc] = o[r][cc];
  if (tx == 0) {
#pragma unroll
    for (int r = 0; r < 4; r++) ob[(4 * ty + r) * DD + 64] = o64[r];
  }
}

extern "C" void kernel_launch(void* const* d_in, const int* in_sizes, int n_in,
                              void* d_out, int out_size, void* d_ws,
                              size_t ws_size, hipStream_t stream) {
  const float* x = (const float*)d_in[0];
  const float* Wq = (const float*)d_in[1];
  const float* Wk = (const float*)d_in[2];
  const float* Wv = (const float*)d_in[3];
  float* out = (float*)d_out;

  // Workspace: P[B*C] padded tiles + T[B] padded tiles.
  int C = 32;
  while (C > 1 && (size_t)(BB * C + BB) * TILE * sizeof(float) > ws_size)
    C >>= 1;
  const int Rc = NN / C;
  float* P = (float*)d_ws;
  float* Tm = P + (size_t)BB * C * TILE;

  k1_gram<<<BB * C, 256, 0, stream>>>(x, P, C, Rc);
  switch (C) {
    case 32: k2_chain<32><<<BB, 256, 0, stream>>>(Wq, Wk, Wv, P, Tm); break;
    case 16: k2_chain<16><<<BB, 256, 0, stream>>>(Wq, Wk, Wv, P, Tm); break;
    case 8:  k2_chain<8><<<BB, 256, 0, stream>>>(Wq, Wk, Wv, P, Tm); break;
    case 4:  k2_chain<4><<<BB, 256, 0, stream>>>(Wq, Wk, Wv, P, Tm); break;
    case 2:  k2_chain<2><<<BB, 256, 0, stream>>>(Wq, Wk, Wv, P, Tm); break;
    default: k2_chain<1><<<BB, 256, 0, stream>>>(Wq, Wk, Wv, P, Tm); break;
  }
  k3_out<<<BB * 32, 256, 0, stream>>>(x, Tm, out);
  (void)in_sizes; (void)n_in; (void)out_size; (void)ws_size;
}